// Round 1
// baseline (277.996 us; speedup 1.0000x reference)
//
#include <hip/hip_runtime.h>
#include <hip/hip_bf16.h>

// Max-margin (hinge) criterion:
//   per row i: s = cossim[i][argmax(target[i])]
//              loss_i = sum_j max(0.1 + cossim[i][j] - s, 0), excluding j==correct
//   out = mean_i(loss_i)
//
// Memory-bound: reads cossim (128 MiB fp32) + target (128 MiB int32) once.
// One wave per row; float4/int4 coalesced loads (16 B/lane).

constexpr int   kC      = 2048;       // choices per row
constexpr float kMargin = 0.1f;

__global__ __launch_bounds__(256) void max_margin_kernel(
    const float* __restrict__ cossim,
    const int*   __restrict__ target,
    float*       __restrict__ out,
    int nrows, float inv_n)
{
    const int lane          = threadIdx.x & 63;
    const int wave_in_block = threadIdx.x >> 6;
    const int wave          = blockIdx.x * 4 + wave_in_block;
    const int nwaves        = gridDim.x * 4;

    float acc = 0.0f;

    for (int row = wave; row < nrows; row += nwaves) {
        const size_t row_off = (size_t)row * kC;

        // ---- pass 1: scan one-hot target (int4 = 16B/lane), find correct sim
        const int4* t = (const int4*)(target + row_off);
        float sim = -3.0e38f;
        #pragma unroll
        for (int k = 0; k < kC / (64 * 4); ++k) {       // 8 iters
            int4 v   = t[lane + k * 64];
            int base = (lane + k * 64) * 4;
            if (v.x == 1) sim = cossim[row_off + base + 0];
            if (v.y == 1) sim = cossim[row_off + base + 1];
            if (v.z == 1) sim = cossim[row_off + base + 2];
            if (v.w == 1) sim = cossim[row_off + base + 3];
        }
        // broadcast across the 64-lane wave (exactly one lane found it)
        #pragma unroll
        for (int off = 32; off > 0; off >>= 1)
            sim = fmaxf(sim, __shfl_xor(sim, off));

        // ---- pass 2: hinge sum over the row (float4 = 16B/lane)
        const float4* c = (const float4*)(cossim + row_off);
        float s = 0.0f;
        #pragma unroll
        for (int k = 0; k < kC / (64 * 4); ++k) {       // 8 iters
            float4 v = c[lane + k * 64];
            s += fmaxf(kMargin + v.x - sim, 0.0f);
            s += fmaxf(kMargin + v.y - sim, 0.0f);
            s += fmaxf(kMargin + v.z - sim, 0.0f);
            s += fmaxf(kMargin + v.w - sim, 0.0f);
        }
        // correct-choice term is exactly max(0.1 + s - s, 0) = 0.1; reference
        // zeroes it via where(target==1) — remove it once per row.
        if (lane == 0) s -= kMargin;
        acc += s;
    }

    // ---- wave reduce
    #pragma unroll
    for (int off = 32; off > 0; off >>= 1)
        acc += __shfl_xor(acc, off);

    // ---- block reduce (4 waves) + one atomic per block
    __shared__ float ws[4];
    if (lane == 0) ws[wave_in_block] = acc;
    __syncthreads();
    if (threadIdx.x == 0) {
        float b = ws[0] + ws[1] + ws[2] + ws[3];
        atomicAdd(out, b * inv_n);
    }
}

extern "C" void kernel_launch(void* const* d_in, const int* in_sizes, int n_in,
                              void* d_out, int out_size, void* d_ws, size_t ws_size,
                              hipStream_t stream)
{
    const float* cossim = (const float*)d_in[0];
    const int*   target = (const int*)d_in[1];
    float*       out    = (float*)d_out;

    const int nrows = in_sizes[0] / kC;          // 16384

    // d_out is poisoned with 0xAA before every launch — zero it (graph-legal).
    hipMemsetAsync(out, 0, sizeof(float), stream);

    const int blocks = (nrows + 3) / 4;          // one wave per row, 4 waves/block
    max_margin_kernel<<<blocks, 256, 0, stream>>>(cossim, target, out,
                                                  nrows, 1.0f / (float)nrows);
}